// Round 1
// baseline (1445.474 us; speedup 1.0000x reference)
//
#include <hip/hip_runtime.h>

#define NN 100000
#define NE 1600000
#define BN_EPS 1e-5f

// ---------------- CSR build ----------------
__global__ __launch_bounds__(256) void k_count(const int* __restrict__ ei, int* __restrict__ deg) {
  int e = blockIdx.x * 256 + threadIdx.x;            // grid covers NE exactly
  atomicAdd(&deg[ei[NE + e]], 1);                    // dst row
}

__global__ __launch_bounds__(256) void k_dinv(const int* __restrict__ deg, float* __restrict__ dinv) {
  int v = blockIdx.x * 256 + threadIdx.x;
  if (v < NN) dinv[v] = rsqrtf((float)deg[v] + 1.0f);  // self-loop weight 1
}

__global__ __launch_bounds__(1024) void k_scan(const int* __restrict__ deg, int* __restrict__ rp) {
  __shared__ int lds[1024];
  const int t = threadIdx.x;
  const int chunk = (NN + 1023) / 1024;              // 98
  int start = t * chunk;
  int end = min(start + chunk, NN);
  int s = 0;
  for (int i = start; i < end; ++i) s += deg[i];
  lds[t] = s;
  __syncthreads();
  for (int d = 1; d < 1024; d <<= 1) {
    int v = (t >= d) ? lds[t - d] : 0;
    __syncthreads();
    lds[t] += v;
    __syncthreads();
  }
  int run = lds[t] - s;                              // exclusive prefix for this chunk
  for (int i = start; i < end; ++i) { rp[i] = run; run += deg[i]; }
  if (t == 1023) rp[NN] = lds[1023];                 // = NE
}

__global__ __launch_bounds__(256) void k_scatter(const int* __restrict__ ei, const int* __restrict__ rp,
                                                 int* __restrict__ fill, int* __restrict__ csr) {
  int e = blockIdx.x * 256 + threadIdx.x;
  int d = ei[NE + e];
  int pos = rp[d] + atomicAdd(&fill[d], 1);
  csr[pos] = ei[e];                                  // src
}

// ---------------- GEMM: hw = h @ W  (fp32 vector) ----------------
// block = 16 rows x 64 cols; W slice transposed into LDS with XOR swizzle so the
// per-lane ds_read_b128 along k is bank-conflict-free; h tile read as uniform broadcast.
__global__ __launch_bounds__(256) void k_gemm(const float* __restrict__ h,
                                              const float* __restrict__ W,
                                              float* __restrict__ hw) {
  __shared__ float wt[64 * 128];                     // [c][k^swz] 32 KiB
  __shared__ float hs[16 * 128];                     // 8 KiB
  const int t = threadIdx.x;
  const int rowblk = blockIdx.x >> 1;
  const int c0 = (blockIdx.x & 1) * 64;
  const int row0 = rowblk * 16;

  for (int idx = t; idx < 64 * 128; idx += 256) {
    int c = idx & 63, k = idx >> 6;                  // coalesced 256B global reads
    wt[c * 128 + (k ^ ((c & 7) << 2))] = W[k * 128 + c0 + c];
  }
  for (int idx = t; idx < 16 * 128; idx += 256)
    hs[idx] = h[row0 * 128 + idx];
  __syncthreads();

  const int col = t & 63, rg = t >> 6;
  const int swz = (col & 7) << 2;
  float acc[4] = {0.f, 0.f, 0.f, 0.f};
  const float* wrow = &wt[col * 128];
  #pragma unroll 8
  for (int k = 0; k < 128; k += 4) {
    const float4 w4 = *(const float4*)(wrow + (k ^ swz));
    #pragma unroll
    for (int j = 0; j < 4; ++j) {
      const float4 h4 = *(const float4*)(hs + (rg + 4 * j) * 128 + k);
      acc[j] = fmaf(w4.x, h4.x, acc[j]);
      acc[j] = fmaf(w4.y, h4.y, acc[j]);
      acc[j] = fmaf(w4.z, h4.z, acc[j]);
      acc[j] = fmaf(w4.w, h4.w, acc[j]);
    }
  }
  #pragma unroll
  for (int j = 0; j < 4; ++j)
    hw[(row0 + rg + 4 * j) * 128 + c0 + col] = acc[j];
}

// ---------------- aggregation: out[v] = dv*sum_e dinv[s]*hw[s] + dv^2*hw[v] + b ----------------
// one wave per node; lane owns 2 features (float2 => 512B coalesced row read per edge)
__global__ __launch_bounds__(256) void k_agg(const float* __restrict__ hw,
                                             const int* __restrict__ rp, const int* __restrict__ csr,
                                             const float* __restrict__ dinv, const float* __restrict__ bias,
                                             float* __restrict__ out) {
  const int wid = (blockIdx.x * 256 + threadIdx.x) >> 6;
  const int lane = threadIdx.x & 63;
  if (wid >= NN) return;
  const int v = wid;
  const int beg = rp[v], end = rp[v + 1];
  float ax = 0.f, ay = 0.f;
  for (int i = beg; i < end; ++i) {
    const int s = csr[i];
    const float ds = dinv[s];
    const float2 val = *(const float2*)(hw + s * 128 + 2 * lane);
    ax = fmaf(ds, val.x, ax);
    ay = fmaf(ds, val.y, ay);
  }
  const float dv = dinv[v];
  const float2 self = *(const float2*)(hw + v * 128 + 2 * lane);
  const float bx = bias[2 * lane], by = bias[2 * lane + 1];
  float2 o;
  o.x = fmaf(ax, dv, fmaf(self.x, dv * dv, bx));
  o.y = fmaf(ay, dv, fmaf(self.y, dv * dv, by));
  *(float2*)(out + v * 128 + 2 * lane) = o;
}

// ---------------- BatchNorm ----------------
__global__ __launch_bounds__(256) void k_bnstats(const float* __restrict__ h, float* __restrict__ stats) {
  __shared__ float rs[256], rs2[256];
  const int t = threadIdx.x;
  const int col = t & 127, rg = t >> 7;
  const int row0 = blockIdx.x * 128;
  const int rend = min(row0 + 128, NN);
  float s = 0.f, s2 = 0.f;
  for (int r = row0 + rg; r < rend; r += 2) {
    float v = h[r * 128 + col];
    s += v;
    s2 = fmaf(v, v, s2);
  }
  rs[t] = s; rs2[t] = s2;
  __syncthreads();
  if (t < 128) {
    atomicAdd(&stats[t], rs[t] + rs[t + 128]);
    atomicAdd(&stats[128 + t], rs2[t] + rs2[t + 128]);
  }
}

__global__ void k_bnfin(const float* __restrict__ stats, const float* __restrict__ gamma,
                        const float* __restrict__ beta, float* __restrict__ sc, float* __restrict__ sh) {
  const int c = threadIdx.x;
  const float inv_n = 1.0f / (float)NN;
  const float mean = stats[c] * inv_n;
  const float var = fmaxf(stats[128 + c] * inv_n - mean * mean, 0.f);
  const float k = gamma[c] * rsqrtf(var + BN_EPS);
  sc[c] = k;
  sh[c] = fmaf(-mean, k, beta[c]);
}

__global__ __launch_bounds__(256) void k_bnrelu(float* __restrict__ h,
                                                const float* __restrict__ sc, const float* __restrict__ sh) {
  const int i = blockIdx.x * 256 + threadIdx.x;      // grid covers NN*128/4 exactly
  const int c = (i & 31) * 4;
  float4 v = ((const float4*)h)[i];
  v.x = fmaxf(fmaf(sc[c + 0], v.x, sh[c + 0]), 0.f);
  v.y = fmaxf(fmaf(sc[c + 1], v.y, sh[c + 1]), 0.f);
  v.z = fmaxf(fmaf(sc[c + 2], v.z, sh[c + 2]), 0.f);
  v.w = fmaxf(fmaf(sc[c + 3], v.w, sh[c + 3]), 0.f);
  ((float4*)h)[i] = v;
}

// ---------------- launch ----------------
extern "C" void kernel_launch(void* const* d_in, const int* in_sizes, int n_in,
                              void* d_out, int out_size, void* d_ws, size_t ws_size,
                              hipStream_t stream) {
  const float* x  = (const float*)d_in[0];
  const int*   ei = (const int*)d_in[1];
  const float* W[3]  = {(const float*)d_in[2],  (const float*)d_in[6],  (const float*)d_in[10]};
  const float* b[3]  = {(const float*)d_in[3],  (const float*)d_in[7],  (const float*)d_in[11]};
  const float* g[3]  = {(const float*)d_in[4],  (const float*)d_in[8],  (const float*)d_in[12]};
  const float* be[3] = {(const float*)d_in[5],  (const float*)d_in[9],  (const float*)d_in[13]};

  char* ws = (char*)d_ws;
  float* hw    = (float*)(ws);                // NN*128 f32 = 51,200,000 B
  int*   csr   = (int*)(ws + 51200000);       // NE ints   =  6,400,000 B
  int*   deg   = (int*)(ws + 57600000);       // NN ints
  int*   rp    = (int*)(ws + 58000000);       // NN+1 ints
  int*   fill  = (int*)(ws + 58400016);       // NN ints
  float* dinv  = (float*)(ws + 58800016);     // NN f32
  float* stats = (float*)(ws + 59200016);     // 256 f32
  float* sc    = (float*)(ws + 59201040);     // 128 f32
  float* sh    = (float*)(ws + 59201552);     // 128 f32
  float* hbuf  = (float*)d_out;               // ping buffer for layer outputs (also final)

  hipMemsetAsync(deg, 0, NN * 4, stream);
  hipMemsetAsync(fill, 0, NN * 4, stream);
  k_count<<<NE / 256, 256, 0, stream>>>(ei, deg);
  k_dinv<<<(NN + 255) / 256, 256, 0, stream>>>(deg, dinv);
  k_scan<<<1, 1024, 0, stream>>>(deg, rp);
  k_scatter<<<NE / 256, 256, 0, stream>>>(ei, rp, fill, csr);

  for (int L = 0; L < 3; ++L) {
    const float* hin = (L == 0) ? x : hbuf;
    k_gemm<<<12500, 256, 0, stream>>>(hin, W[L], hw);
    k_agg<<<25000, 256, 0, stream>>>(hw, rp, csr, dinv, b[L], hbuf);
    hipMemsetAsync(stats, 0, 256 * 4, stream);
    k_bnstats<<<(NN + 127) / 128, 256, 0, stream>>>(hbuf, stats);
    k_bnfin<<<1, 128, 0, stream>>>(stats, g[L], be[L], sc, sh);
    k_bnrelu<<<NN * 128 / 1024, 256, 0, stream>>>(hbuf, sc, sh);
  }
}

// Round 2
// 885.751 us; speedup vs baseline: 1.6319x; 1.6319x over previous
//
#include <hip/hip_runtime.h>
#include <hip/hip_bf16.h>

#define NN 100000
#define NE 1600000
#define BN_EPS 1e-5f

typedef __attribute__((ext_vector_type(8))) short bf16x8;
typedef __attribute__((ext_vector_type(4))) float f32x4;

static __device__ __forceinline__ ushort f2b(float f) {
  __hip_bfloat16 h = __float2bfloat16(f);            // RNE
  return __builtin_bit_cast(ushort, h);
}
static __device__ __forceinline__ float blo(uint v) { return __builtin_bit_cast(float, v << 16); }
static __device__ __forceinline__ float bhi(uint v) { return __builtin_bit_cast(float, v & 0xFFFF0000u); }

// ---------------- CSR build ----------------
__global__ __launch_bounds__(256) void k_count(const int* __restrict__ ei, int* __restrict__ deg) {
  int e = blockIdx.x * 256 + threadIdx.x;
  atomicAdd(&deg[ei[NE + e]], 1);
}

__global__ __launch_bounds__(256) void k_dinv(const int* __restrict__ deg, float* __restrict__ dinv) {
  int v = blockIdx.x * 256 + threadIdx.x;
  if (v < NN) dinv[v] = rsqrtf((float)deg[v] + 1.0f);
}

__global__ __launch_bounds__(1024) void k_scan(const int* __restrict__ deg, int* __restrict__ rp) {
  __shared__ int lds[1024];
  const int t = threadIdx.x;
  const int chunk = (NN + 1023) / 1024;
  int start = t * chunk;
  int end = min(start + chunk, NN);
  int s = 0;
  for (int i = start; i < end; ++i) s += deg[i];
  lds[t] = s;
  __syncthreads();
  for (int d = 1; d < 1024; d <<= 1) {
    int v = (t >= d) ? lds[t - d] : 0;
    __syncthreads();
    lds[t] += v;
    __syncthreads();
  }
  int run = lds[t] - s;
  for (int i = start; i < end; ++i) { rp[i] = run; run += deg[i]; }
  if (t == 1023) rp[NN] = lds[1023];
}

__global__ __launch_bounds__(256) void k_scatter(const int* __restrict__ ei, const int* __restrict__ rp,
                                                 int* __restrict__ fill, int* __restrict__ csr) {
  int e = blockIdx.x * 256 + threadIdx.x;
  int d = ei[NE + e];
  int pos = rp[d] + atomicAdd(&fill[d], 1);
  csr[pos] = ei[e];
}

// ---------------- W prep: wt[layer][n][k] = bf16(W[k][n]) ----------------
__global__ __launch_bounds__(128) void k_wt(const float* __restrict__ W0, const float* __restrict__ W1,
                                            const float* __restrict__ W2, ushort* __restrict__ wt) {
  const int lay = blockIdx.y, n = blockIdx.x, k = threadIdx.x;
  const float* W = (lay == 0) ? W0 : (lay == 1) ? W1 : W2;
  wt[lay * 16384 + n * 128 + k] = f2b(W[k * 128 + n]);
}

// ---------------- x -> bf16 ----------------
__global__ __launch_bounds__(256) void k_tobf(const float* __restrict__ x, ushort* __restrict__ o) {
  int i = blockIdx.x * 256 + threadIdx.x;            // grid covers NN*128/4 exactly
  float4 v = ((const float4*)x)[i];
  ushort4 u;
  u.x = f2b(v.x); u.y = f2b(v.y); u.z = f2b(v.z); u.w = f2b(v.w);
  ((ushort4*)o)[i] = u;
}

// ---------------- GEMM (MFMA bf16): hw = h @ W ----------------
// block = 128 rows, 4 waves x 32 rows. W^T staged in LDS with 16B-chunk XOR swizzle.
__global__ __launch_bounds__(256) void k_gemm(const ushort* __restrict__ h,
                                              const ushort* __restrict__ wt,   // [n][k] bf16
                                              ushort* __restrict__ hw) {
  __shared__ ushort wlds[128 * 128];                 // 32 KiB
  const int t = threadIdx.x;
  {
    const uint4* src = (const uint4*)wt;
    uint4* dst = (uint4*)wlds;
    #pragma unroll
    for (int i = 0; i < 8; ++i) {
      int idx = t + i * 256;                         // 16B-chunk index, 2048 total
      int n = idx >> 4;
      dst[idx ^ (n & 7)] = src[idx];                 // swizzle chunks within each 256B row
    }
  }
  __syncthreads();

  const int wv = t >> 6, l = t & 63;
  const int lr = l & 15, lk = l >> 4;                // lane row/col within tile, k-group
  const int row0 = blockIdx.x * 128 + wv * 32;
  f32x4 acc[2][8] = {};
  const uint4* wchunks = (const uint4*)wlds;

  #pragma unroll
  for (int kb = 0; kb < 4; ++kb) {
    const int r0 = min(row0 + lr, NN - 1);
    const int r1 = min(row0 + 16 + lr, NN - 1);
    const bf16x8 a0 = *(const bf16x8*)(h + (size_t)r0 * 128 + kb * 32 + lk * 8);
    const bf16x8 a1 = *(const bf16x8*)(h + (size_t)r1 * 128 + kb * 32 + lk * 8);
    #pragma unroll
    for (int nt = 0; nt < 8; ++nt) {
      const int n = nt * 16 + lr;
      const int chunk = n * 16 + ((kb * 4 + lk) ^ (n & 7));
      const bf16x8 b = *(const bf16x8*)(wchunks + chunk);
      acc[0][nt] = __builtin_amdgcn_mfma_f32_16x16x32_bf16(a0, b, acc[0][nt], 0, 0, 0);
      acc[1][nt] = __builtin_amdgcn_mfma_f32_16x16x32_bf16(a1, b, acc[1][nt], 0, 0, 0);
    }
  }
  // D layout: col = lane&15, row = (lane>>4)*4 + j  [m89]
  #pragma unroll
  for (int rt = 0; rt < 2; ++rt)
    #pragma unroll
    for (int j = 0; j < 4; ++j) {
      const int row = row0 + rt * 16 + lk * 4 + j;
      if (row < NN) {
        #pragma unroll
        for (int nt = 0; nt < 8; ++nt)
          hw[(size_t)row * 128 + nt * 16 + lr] = f2b(acc[rt][nt][j]);
      }
    }
}

// ---------------- aggregation (bf16 gather) ----------------
__global__ __launch_bounds__(256) void k_agg(const ushort* __restrict__ hw,
                                             const int* __restrict__ rp, const int* __restrict__ csr,
                                             const float* __restrict__ dinv, const float* __restrict__ bias,
                                             float* __restrict__ out) {
  const int wid = (blockIdx.x * 256 + threadIdx.x) >> 6;
  const int lane = threadIdx.x & 63;
  if (wid >= NN) return;
  const int v = wid;
  const int beg = rp[v], end = rp[v + 1];
  float ax = 0.f, ay = 0.f;
  int i = beg;
  for (; i + 4 <= end; i += 4) {                     // 4-deep MLP: independent load chains
    const int s0 = csr[i], s1 = csr[i + 1], s2 = csr[i + 2], s3 = csr[i + 3];
    const float d0 = dinv[s0], d1 = dinv[s1], d2 = dinv[s2], d3 = dinv[s3];
    const uint v0 = *(const uint*)(hw + (size_t)s0 * 128 + 2 * lane);
    const uint v1 = *(const uint*)(hw + (size_t)s1 * 128 + 2 * lane);
    const uint v2 = *(const uint*)(hw + (size_t)s2 * 128 + 2 * lane);
    const uint v3 = *(const uint*)(hw + (size_t)s3 * 128 + 2 * lane);
    ax = fmaf(d0, blo(v0), ax); ay = fmaf(d0, bhi(v0), ay);
    ax = fmaf(d1, blo(v1), ax); ay = fmaf(d1, bhi(v1), ay);
    ax = fmaf(d2, blo(v2), ax); ay = fmaf(d2, bhi(v2), ay);
    ax = fmaf(d3, blo(v3), ax); ay = fmaf(d3, bhi(v3), ay);
  }
  for (; i < end; ++i) {
    const int s = csr[i];
    const float ds = dinv[s];
    const uint vv = *(const uint*)(hw + (size_t)s * 128 + 2 * lane);
    ax = fmaf(ds, blo(vv), ax); ay = fmaf(ds, bhi(vv), ay);
  }
  const float dv = dinv[v];
  const uint sv = *(const uint*)(hw + (size_t)v * 128 + 2 * lane);
  const float bx = bias[2 * lane], by = bias[2 * lane + 1];
  float2 o;
  o.x = fmaf(ax, dv, fmaf(blo(sv), dv * dv, bx));
  o.y = fmaf(ay, dv, fmaf(bhi(sv), dv * dv, by));
  *(float2*)(out + (size_t)v * 128 + 2 * lane) = o;
}

// ---------------- BatchNorm ----------------
__global__ __launch_bounds__(256) void k_bnstats(const float* __restrict__ h, float* __restrict__ stats) {
  __shared__ float rs[256], rs2[256];
  const int t = threadIdx.x;
  const int col = t & 127, rg = t >> 7;
  const int row0 = blockIdx.x * 128;
  const int rend = min(row0 + 128, NN);
  float s = 0.f, s2 = 0.f;
  for (int r = row0 + rg; r < rend; r += 2) {
    float v = h[(size_t)r * 128 + col];
    s += v;
    s2 = fmaf(v, v, s2);
  }
  rs[t] = s; rs2[t] = s2;
  __syncthreads();
  if (t < 128) {
    atomicAdd(&stats[t], rs[t] + rs[t + 128]);
    atomicAdd(&stats[128 + t], rs2[t] + rs2[t + 128]);
  }
}

__global__ void k_bnfin(const float* __restrict__ stats, const float* __restrict__ gamma,
                        const float* __restrict__ beta, float* __restrict__ sc, float* __restrict__ sh) {
  const int c = threadIdx.x;
  const float inv_n = 1.0f / (float)NN;
  const float mean = stats[c] * inv_n;
  const float var = fmaxf(stats[128 + c] * inv_n - mean * mean, 0.f);
  const float k = gamma[c] * rsqrtf(var + BN_EPS);
  sc[c] = k;
  sh[c] = fmaf(-mean, k, beta[c]);
}

// reads fp32 agg output, writes bf16 next-layer input; fp32 final output only when asked
__global__ __launch_bounds__(256) void k_bnrelu(const float* __restrict__ h, ushort* __restrict__ ob,
                                                float* __restrict__ of, const int write_f32,
                                                const float* __restrict__ sc, const float* __restrict__ sh) {
  const int i = blockIdx.x * 256 + threadIdx.x;      // grid covers NN*128/4 exactly
  const int c = (i & 31) * 4;
  float4 v = ((const float4*)h)[i];
  v.x = fmaxf(fmaf(sc[c + 0], v.x, sh[c + 0]), 0.f);
  v.y = fmaxf(fmaf(sc[c + 1], v.y, sh[c + 1]), 0.f);
  v.z = fmaxf(fmaf(sc[c + 2], v.z, sh[c + 2]), 0.f);
  v.w = fmaxf(fmaf(sc[c + 3], v.w, sh[c + 3]), 0.f);
  ushort4 u;
  u.x = f2b(v.x); u.y = f2b(v.y); u.z = f2b(v.z); u.w = f2b(v.w);
  ((ushort4*)ob)[i] = u;
  if (write_f32) ((float4*)of)[i] = v;
}

// ---------------- launch ----------------
extern "C" void kernel_launch(void* const* d_in, const int* in_sizes, int n_in,
                              void* d_out, int out_size, void* d_ws, size_t ws_size,
                              hipStream_t stream) {
  const float* x  = (const float*)d_in[0];
  const int*   ei = (const int*)d_in[1];
  const float* W[3]  = {(const float*)d_in[2],  (const float*)d_in[6],  (const float*)d_in[10]};
  const float* b[3]  = {(const float*)d_in[3],  (const float*)d_in[7],  (const float*)d_in[11]};
  const float* g[3]  = {(const float*)d_in[4],  (const float*)d_in[8],  (const float*)d_in[12]};
  const float* be[3] = {(const float*)d_in[5],  (const float*)d_in[9],  (const float*)d_in[13]};

  char* ws = (char*)d_ws;
  ushort* hwb   = (ushort*)(ws);                // NN*128 bf16 = 25,600,000 B
  ushort* hin   = (ushort*)(ws + 25600000);     // NN*128 bf16 (layer input, ping)
  int*    csr   = (int*)(ws + 51200000);        // NE ints
  int*    deg   = (int*)(ws + 57600000);
  int*    rp    = (int*)(ws + 58000000);
  int*    fill  = (int*)(ws + 58400016);
  float*  dinv  = (float*)(ws + 58800016);
  ushort* wtb   = (ushort*)(ws + 59200016);     // 3 x 128x128 bf16 (W^T)
  float*  stats = (float*)(ws + 59298320);
  float*  sc    = (float*)(ws + 59299344);
  float*  sh    = (float*)(ws + 59299856);
  float*  hbuf  = (float*)d_out;                // fp32 agg/BN buffer (also final output)

  hipMemsetAsync(deg, 0, NN * 4, stream);
  hipMemsetAsync(fill, 0, NN * 4, stream);
  k_count<<<NE / 256, 256, 0, stream>>>(ei, deg);
  k_dinv<<<(NN + 255) / 256, 256, 0, stream>>>(deg, dinv);
  k_scan<<<1, 1024, 0, stream>>>(deg, rp);
  k_scatter<<<NE / 256, 256, 0, stream>>>(ei, rp, fill, csr);
  k_wt<<<dim3(128, 3), 128, 0, stream>>>(W[0], W[1], W[2], wtb);
  k_tobf<<<NN * 128 / 1024, 256, 0, stream>>>(x, hin);

  for (int L = 0; L < 3; ++L) {
    k_gemm<<<(NN + 127) / 128, 256, 0, stream>>>(hin, wtb + L * 16384, hwb);
    k_agg<<<25000, 256, 0, stream>>>(hwb, rp, csr, dinv, b[L], hbuf);
    hipMemsetAsync(stats, 0, 256 * 4, stream);
    k_bnstats<<<(NN + 127) / 128, 256, 0, stream>>>(hbuf, stats);
    k_bnfin<<<1, 128, 0, stream>>>(stats, g[L], be[L], sc, sh);
    k_bnrelu<<<NN * 128 / 1024, 256, 0, stream>>>(hbuf, hin, hbuf, (L == 2) ? 1 : 0, sc, sh);
  }
}

// Round 3
// 764.524 us; speedup vs baseline: 1.8907x; 1.1586x over previous
//
#include <hip/hip_runtime.h>
#include <hip/hip_bf16.h>

#define NN 100000
#define NE 1600000
#define BN_EPS 1e-5f
#define NB 391                                      // ceil(NN/256)

typedef __attribute__((ext_vector_type(8))) short bf16x8;
typedef __attribute__((ext_vector_type(4))) float f32x4;

static __device__ __forceinline__ ushort f2b(float f) {
  __hip_bfloat16 h = __float2bfloat16(f);            // RNE
  return __builtin_bit_cast(ushort, h);
}
static __device__ __forceinline__ float blo(uint v) { return __builtin_bit_cast(float, v << 16); }
static __device__ __forceinline__ float bhi(uint v) { return __builtin_bit_cast(float, v & 0xFFFF0000u); }

// ---------------- CSR build ----------------
__global__ __launch_bounds__(256) void k_count(const int* __restrict__ ei, int* __restrict__ deg) {
  int e = blockIdx.x * 256 + threadIdx.x;
  atomicAdd(&deg[ei[NE + e]], 1);
}

__global__ __launch_bounds__(256) void k_dinv(const int* __restrict__ deg, float* __restrict__ dinv) {
  int v = blockIdx.x * 256 + threadIdx.x;
  if (v < NN) dinv[v] = rsqrtf((float)deg[v] + 1.0f);
}

// level 1: per-block sums of deg
__global__ __launch_bounds__(256) void k_scan1(const int* __restrict__ deg, int* __restrict__ bsum) {
  __shared__ int lds[256];
  const int t = threadIdx.x;
  const int i = blockIdx.x * 256 + t;
  lds[t] = (i < NN) ? deg[i] : 0;
  __syncthreads();
  for (int d = 128; d > 0; d >>= 1) {
    if (t < d) lds[t] += lds[t + d];
    __syncthreads();
  }
  if (t == 0) bsum[blockIdx.x] = lds[0];
}

// level 2: scan the NB block sums (single block, 512 threads)
__global__ __launch_bounds__(512) void k_scan2(const int* __restrict__ bsum, int* __restrict__ boff,
                                               int* __restrict__ rp) {
  __shared__ int lds[512];
  const int t = threadIdx.x;
  const int own = (t < NB) ? bsum[t] : 0;
  lds[t] = own;
  __syncthreads();
  for (int d = 1; d < 512; d <<= 1) {
    int v = (t >= d) ? lds[t - d] : 0;
    __syncthreads();
    lds[t] += v;
    __syncthreads();
  }
  if (t < NB) boff[t] = lds[t] - own;                // exclusive block offset
  if (t == 511) rp[NN] = lds[511];                   // total = NE
}

// level 3: in-block exclusive scan + block offset
__global__ __launch_bounds__(256) void k_scan3(const int* __restrict__ deg, const int* __restrict__ boff,
                                               int* __restrict__ rp) {
  __shared__ int lds[256];
  const int t = threadIdx.x;
  const int i = blockIdx.x * 256 + t;
  const int own = (i < NN) ? deg[i] : 0;
  lds[t] = own;
  __syncthreads();
  for (int d = 1; d < 256; d <<= 1) {
    int v = (t >= d) ? lds[t - d] : 0;
    __syncthreads();
    lds[t] += v;
    __syncthreads();
  }
  if (i < NN) rp[i] = boff[blockIdx.x] + lds[t] - own;
}

__global__ __launch_bounds__(256) void k_scatter(const int* __restrict__ ei, const int* __restrict__ rp,
                                                 int* __restrict__ fill, int* __restrict__ csr) {
  int e = blockIdx.x * 256 + threadIdx.x;
  int d = ei[NE + e];
  int pos = rp[d] + atomicAdd(&fill[d], 1);
  csr[pos] = ei[e];
}

// ---------------- W prep: wt[layer][n][k] = bf16(W[k][n]) ----------------
__global__ __launch_bounds__(128) void k_wt(const float* __restrict__ W0, const float* __restrict__ W1,
                                            const float* __restrict__ W2, ushort* __restrict__ wt) {
  const int lay = blockIdx.y, n = blockIdx.x, k = threadIdx.x;
  const float* W = (lay == 0) ? W0 : (lay == 1) ? W1 : W2;
  wt[lay * 16384 + n * 128 + k] = f2b(W[k * 128 + n]);
}

// ---------------- x -> bf16 ----------------
__global__ __launch_bounds__(256) void k_tobf(const float* __restrict__ x, ushort* __restrict__ o) {
  int i = blockIdx.x * 256 + threadIdx.x;            // grid covers NN*128/4 exactly
  float4 v = ((const float4*)x)[i];
  ushort4 u;
  u.x = f2b(v.x); u.y = f2b(v.y); u.z = f2b(v.z); u.w = f2b(v.w);
  ((ushort4*)o)[i] = u;
}

// ---------------- GEMM (MFMA bf16): hw = h @ W ----------------
__global__ __launch_bounds__(256) void k_gemm(const ushort* __restrict__ h,
                                              const ushort* __restrict__ wt,   // [n][k] bf16
                                              ushort* __restrict__ hw) {
  __shared__ ushort wlds[128 * 128];                 // 32 KiB
  const int t = threadIdx.x;
  {
    const uint4* src = (const uint4*)wt;
    uint4* dst = (uint4*)wlds;
    #pragma unroll
    for (int i = 0; i < 8; ++i) {
      int idx = t + i * 256;                         // 16B-chunk index, 2048 total
      int n = idx >> 4;
      dst[idx ^ (n & 7)] = src[idx];                 // swizzle chunks within each 256B row
    }
  }
  __syncthreads();

  const int wv = t >> 6, l = t & 63;
  const int lr = l & 15, lk = l >> 4;
  const int row0 = blockIdx.x * 128 + wv * 32;
  f32x4 acc[2][8] = {};
  const uint4* wchunks = (const uint4*)wlds;

  #pragma unroll
  for (int kb = 0; kb < 4; ++kb) {
    const int r0 = min(row0 + lr, NN - 1);
    const int r1 = min(row0 + 16 + lr, NN - 1);
    const bf16x8 a0 = *(const bf16x8*)(h + (size_t)r0 * 128 + kb * 32 + lk * 8);
    const bf16x8 a1 = *(const bf16x8*)(h + (size_t)r1 * 128 + kb * 32 + lk * 8);
    #pragma unroll
    for (int nt = 0; nt < 8; ++nt) {
      const int n = nt * 16 + lr;
      const int chunk = n * 16 + ((kb * 4 + lk) ^ (n & 7));
      const bf16x8 b = *(const bf16x8*)(wchunks + chunk);
      acc[0][nt] = __builtin_amdgcn_mfma_f32_16x16x32_bf16(a0, b, acc[0][nt], 0, 0, 0);
      acc[1][nt] = __builtin_amdgcn_mfma_f32_16x16x32_bf16(a1, b, acc[1][nt], 0, 0, 0);
    }
  }
  #pragma unroll
  for (int rt = 0; rt < 2; ++rt)
    #pragma unroll
    for (int j = 0; j < 4; ++j) {
      const int row = row0 + rt * 16 + lk * 4 + j;
      if (row < NN) {
        #pragma unroll
        for (int nt = 0; nt < 8; ++nt)
          hw[(size_t)row * 128 + nt * 16 + lr] = f2b(acc[rt][nt][j]);
      }
    }
}

// ---------------- aggregation (bf16 gather) ----------------
__global__ __launch_bounds__(256) void k_agg(const ushort* __restrict__ hw,
                                             const int* __restrict__ rp, const int* __restrict__ csr,
                                             const float* __restrict__ dinv, const float* __restrict__ bias,
                                             float* __restrict__ out) {
  const int wid = (blockIdx.x * 256 + threadIdx.x) >> 6;
  const int lane = threadIdx.x & 63;
  if (wid >= NN) return;
  const int v = wid;
  const int beg = rp[v], end = rp[v + 1];
  float ax = 0.f, ay = 0.f;
  int i = beg;
  for (; i + 4 <= end; i += 4) {
    const int s0 = csr[i], s1 = csr[i + 1], s2 = csr[i + 2], s3 = csr[i + 3];
    const float d0 = dinv[s0], d1 = dinv[s1], d2 = dinv[s2], d3 = dinv[s3];
    const uint v0 = *(const uint*)(hw + (size_t)s0 * 128 + 2 * lane);
    const uint v1 = *(const uint*)(hw + (size_t)s1 * 128 + 2 * lane);
    const uint v2 = *(const uint*)(hw + (size_t)s2 * 128 + 2 * lane);
    const uint v3 = *(const uint*)(hw + (size_t)s3 * 128 + 2 * lane);
    ax = fmaf(d0, blo(v0), ax); ay = fmaf(d0, bhi(v0), ay);
    ax = fmaf(d1, blo(v1), ax); ay = fmaf(d1, bhi(v1), ay);
    ax = fmaf(d2, blo(v2), ax); ay = fmaf(d2, bhi(v2), ay);
    ax = fmaf(d3, blo(v3), ax); ay = fmaf(d3, bhi(v3), ay);
  }
  for (; i < end; ++i) {
    const int s = csr[i];
    const float ds = dinv[s];
    const uint vv = *(const uint*)(hw + (size_t)s * 128 + 2 * lane);
    ax = fmaf(ds, blo(vv), ax); ay = fmaf(ds, bhi(vv), ay);
  }
  const float dv = dinv[v];
  const uint sv = *(const uint*)(hw + (size_t)v * 128 + 2 * lane);
  const float bx = bias[2 * lane], by = bias[2 * lane + 1];
  float2 o;
  o.x = fmaf(ax, dv, fmaf(blo(sv), dv * dv, bx));
  o.y = fmaf(ay, dv, fmaf(bhi(sv), dv * dv, by));
  *(float2*)(out + (size_t)v * 128 + 2 * lane) = o;
}

// ---------------- BatchNorm ----------------
__global__ __launch_bounds__(256) void k_bnstats(const float* __restrict__ h, float* __restrict__ stats) {
  __shared__ float rs[256], rs2[256];
  const int t = threadIdx.x;
  const int col = t & 127, rg = t >> 7;
  const int row0 = blockIdx.x * 128;
  const int rend = min(row0 + 128, NN);
  float s = 0.f, s2 = 0.f;
  for (int r = row0 + rg; r < rend; r += 2) {
    float v = h[(size_t)r * 128 + col];
    s += v;
    s2 = fmaf(v, v, s2);
  }
  rs[t] = s; rs2[t] = s2;
  __syncthreads();
  if (t < 128) {
    atomicAdd(&stats[t], rs[t] + rs[t + 128]);
    atomicAdd(&stats[128 + t], rs2[t] + rs2[t + 128]);
  }
}

__global__ void k_bnfin(const float* __restrict__ stats, const float* __restrict__ gamma,
                        const float* __restrict__ beta, float* __restrict__ sc, float* __restrict__ sh) {
  const int c = threadIdx.x;
  const float inv_n = 1.0f / (float)NN;
  const float mean = stats[c] * inv_n;
  const float var = fmaxf(stats[128 + c] * inv_n - mean * mean, 0.f);
  const float k = gamma[c] * rsqrtf(var + BN_EPS);
  sc[c] = k;
  sh[c] = fmaf(-mean, k, beta[c]);
}

__global__ __launch_bounds__(256) void k_bnrelu(const float* __restrict__ h, ushort* __restrict__ ob,
                                                float* __restrict__ of, const int write_f32,
                                                const float* __restrict__ sc, const float* __restrict__ sh) {
  const int i = blockIdx.x * 256 + threadIdx.x;      // grid covers NN*128/4 exactly
  const int c = (i & 31) * 4;
  float4 v = ((const float4*)h)[i];
  v.x = fmaxf(fmaf(sc[c + 0], v.x, sh[c + 0]), 0.f);
  v.y = fmaxf(fmaf(sc[c + 1], v.y, sh[c + 1]), 0.f);
  v.z = fmaxf(fmaf(sc[c + 2], v.z, sh[c + 2]), 0.f);
  v.w = fmaxf(fmaf(sc[c + 3], v.w, sh[c + 3]), 0.f);
  ushort4 u;
  u.x = f2b(v.x); u.y = f2b(v.y); u.z = f2b(v.z); u.w = f2b(v.w);
  ((ushort4*)ob)[i] = u;
  if (write_f32) ((float4*)of)[i] = v;
}

// ---------------- launch ----------------
extern "C" void kernel_launch(void* const* d_in, const int* in_sizes, int n_in,
                              void* d_out, int out_size, void* d_ws, size_t ws_size,
                              hipStream_t stream) {
  const float* x  = (const float*)d_in[0];
  const int*   ei = (const int*)d_in[1];
  const float* W[3]  = {(const float*)d_in[2],  (const float*)d_in[6],  (const float*)d_in[10]};
  const float* b[3]  = {(const float*)d_in[3],  (const float*)d_in[7],  (const float*)d_in[11]};
  const float* g[3]  = {(const float*)d_in[4],  (const float*)d_in[8],  (const float*)d_in[12]};
  const float* be[3] = {(const float*)d_in[5],  (const float*)d_in[9],  (const float*)d_in[13]};

  char* ws = (char*)d_ws;
  ushort* hwb   = (ushort*)(ws);                // NN*128 bf16 = 25,600,000 B
  ushort* hin   = (ushort*)(ws + 25600000);     // NN*128 bf16 (layer input)
  int*    csr   = (int*)(ws + 51200000);        // NE ints
  int*    deg   = (int*)(ws + 57600000);
  int*    rp    = (int*)(ws + 58000000);
  int*    fill  = (int*)(ws + 58400016);
  float*  dinv  = (float*)(ws + 58800016);
  ushort* wtb   = (ushort*)(ws + 59200016);     // 3 x 128x128 bf16 (W^T)
  float*  stats = (float*)(ws + 59298320);
  float*  sc    = (float*)(ws + 59299344);
  float*  sh    = (float*)(ws + 59299856);
  int*    bsum  = (int*)(ws + 59300368);        // NB ints
  int*    boff  = (int*)(ws + 59301936);        // NB ints
  float*  hbuf  = (float*)d_out;                // fp32 agg/BN buffer (also final output)

  hipMemsetAsync(deg, 0, NN * 4, stream);
  hipMemsetAsync(fill, 0, NN * 4, stream);
  k_count<<<NE / 256, 256, 0, stream>>>(ei, deg);
  k_dinv<<<(NN + 255) / 256, 256, 0, stream>>>(deg, dinv);
  k_scan1<<<NB, 256, 0, stream>>>(deg, bsum);
  k_scan2<<<1, 512, 0, stream>>>(bsum, boff, rp);
  k_scan3<<<NB, 256, 0, stream>>>(deg, boff, rp);
  k_scatter<<<NE / 256, 256, 0, stream>>>(ei, rp, fill, csr);
  k_wt<<<dim3(128, 3), 128, 0, stream>>>(W[0], W[1], W[2], wtb);
  k_tobf<<<NN * 128 / 1024, 256, 0, stream>>>(x, hin);

  for (int L = 0; L < 3; ++L) {
    k_gemm<<<(NN + 127) / 128, 256, 0, stream>>>(hin, wtb + L * 16384, hwb);
    k_agg<<<25000, 256, 0, stream>>>(hwb, rp, csr, dinv, b[L], hbuf);
    hipMemsetAsync(stats, 0, 256 * 4, stream);
    k_bnstats<<<(NN + 127) / 128, 256, 0, stream>>>(hbuf, stats);
    k_bnfin<<<1, 128, 0, stream>>>(stats, g[L], be[L], sc, sh);
    k_bnrelu<<<NN * 128 / 1024, 256, 0, stream>>>(hbuf, hin, hbuf, (L == 2) ? 1 : 0, sc, sh);
  }
}